// Round 4
// baseline (1643.585 us; speedup 1.0000x reference)
//
#include <hip/hip_runtime.h>

#define N_NODES 50000
#define N_EDGES 1600000
#define D_IN 192
#define D_HID 128
#define NBUK 196            // ceil(50000/256) dst buckets of 256
#define BCAP 9216           // bucket capacity (avg 8163, +11 sigma)

typedef __bf16 bf16x8 __attribute__((ext_vector_type(8)));
typedef float f32x4 __attribute__((ext_vector_type(4)));

__device__ __forceinline__ unsigned short f2b(float x) {
    unsigned u = __builtin_bit_cast(unsigned, x);
    u += 0x7FFFu + ((u >> 16) & 1u);          // round-to-nearest-even
    return (unsigned short)(u >> 16);
}
__device__ __forceinline__ float blo(unsigned u) {
    return __builtin_bit_cast(float, u << 16);
}
__device__ __forceinline__ float bhi(unsigned u) {
    return __builtin_bit_cast(float, u & 0xFFFF0000u);
}

// ---------------- CSR build: bucket sort ----------------

// Pass 1: scatter packed (dst<<16|src) into coarse buckets. Concurrent same-
// bucket writers get consecutive slots -> line-coalesced writes.
__global__ void scatter_buckets(const int* __restrict__ src, const int* __restrict__ dst,
        int E, int* __restrict__ bcnt, unsigned* __restrict__ bbuf) {
    int e = blockIdx.x * 256 + threadIdx.x;
    if (e < E) {
        int d = dst[e];
        int b = d >> 8;
        int slot = atomicAdd(&bcnt[b], 1);
        if (slot < BCAP)
            bbuf[(size_t)b * BCAP + slot] = ((unsigned)d << 16) | (unsigned)src[e];
    }
}

// Pass 2a: per-dst counts from bucket contents (coalesced reads, LDS atomics).
__global__ __launch_bounds__(256) void bucket_count(const int* __restrict__ bcnt,
        const unsigned* __restrict__ bbuf, int* __restrict__ cnt, int n) {
    __shared__ int bins[256];
    int b = blockIdx.x, t = threadIdx.x;
    bins[t] = 0;
    __syncthreads();
    int m = min(bcnt[b], BCAP);
    for (int i = t; i < m; i += 256)
        atomicAdd(&bins[(bbuf[(size_t)b * BCAP + i] >> 16) & 255], 1);
    __syncthreads();
    int i = (b << 8) + t;
    if (i < n) cnt[i] = bins[t];
}

// Pass 2b: place srcs dst-sorted in LDS, then ONE contiguous coalesced copy out.
__global__ __launch_bounds__(256) void bucket_place(const int* __restrict__ bcnt,
        const unsigned* __restrict__ bbuf, const int* __restrict__ row_ptr,
        unsigned short* __restrict__ esrc, int n) {
    __shared__ int off[256];
    __shared__ int fil[256];
    __shared__ unsigned short ls[BCAP];
    int b = blockIdx.x, t = threadIdx.x;
    int base = b << 8;
    int gbase = row_ptr[base];            // base <= 49920 < n always
    int idx = base + t;
    off[t] = (idx < n) ? (row_ptr[idx] - gbase) : 0;
    fil[t] = 0;
    __syncthreads();
    int m = min(bcnt[b], BCAP);
    for (int i = t; i < m; i += 256) {
        unsigned u = bbuf[(size_t)b * BCAP + i];
        int dl = (u >> 16) & 255;
        int pos = off[dl] + atomicAdd(&fil[dl], 1);
        ls[pos] = (unsigned short)(u & 0xFFFFu);
    }
    __syncthreads();
    for (int i = t; i < m; i += 256) esrc[gbase + i] = ls[i];
}

// ---------------- prefix scans for row_ptr ----------------

__global__ __launch_bounds__(256) void block_sums(const int* __restrict__ cnt, int n,
        int* __restrict__ bsum, float* __restrict__ dhis) {
    __shared__ int sh[256];
    int t = threadIdx.x;
    int i = blockIdx.x * 256 + t;
    int c = (i < n) ? cnt[i] : 0;
    if (i < n) dhis[i] = rsqrtf((float)c + 1.0f);
    sh[t] = c;
    __syncthreads();
    for (int o = 128; o > 0; o >>= 1) {
        if (t < o) sh[t] += sh[t + o];
        __syncthreads();
    }
    if (t == 0) bsum[blockIdx.x] = sh[0];
}

__global__ __launch_bounds__(256) void scan_bsums(const int* __restrict__ bsum, int nb,
        int* __restrict__ boff, int* __restrict__ row_ptr, int n) {
    __shared__ int sh[256];
    int t = threadIdx.x;
    int v = (t < nb) ? bsum[t] : 0;
    sh[t] = v;
    __syncthreads();
    for (int o = 1; o < 256; o <<= 1) {
        int a = (t >= o) ? sh[t - o] : 0;
        __syncthreads();
        sh[t] += a;
        __syncthreads();
    }
    if (t < nb) boff[t] = sh[t] - v;
    if (t == 255) row_ptr[n] = sh[255];
}

__global__ __launch_bounds__(256) void block_scan(const int* __restrict__ cnt, int n,
        const int* __restrict__ boff, int* __restrict__ row_ptr) {
    __shared__ int sh[256];
    int t = threadIdx.x;
    int i = blockIdx.x * 256 + t;
    int c = (i < n) ? cnt[i] : 0;
    sh[t] = c;
    __syncthreads();
    for (int o = 1; o < 256; o <<= 1) {
        int a = (t >= o) ? sh[t - o] : 0;
        __syncthreads();
        sh[t] += a;
        __syncthreads();
    }
    if (i < n) row_ptr[i] = boff[blockIdx.x] + sh[t] - c;
}

// ---------------- weight prep: Wt[j][k] = bf16(W[k][j]) ----------------

struct WP { const float* w; unsigned short* wt; int K; };

__global__ void prep_all(WP p0, WP p1, WP p2, WP p3, WP p4, WP p5) {
    WP p;
    switch (blockIdx.y) {
        case 0: p = p0; break; case 1: p = p1; break; case 2: p = p2; break;
        case 3: p = p3; break; case 4: p = p4; break; default: p = p5; break;
    }
    int idx = blockIdx.x * 256 + threadIdx.x;
    if (idx < 128 * p.K) {
        int j = idx / p.K, k = idx - j * p.K;
        p.wt[idx] = f2b(p.w[(size_t)k * 128 + j]);
    }
}

// ---------------- MFMA GEMM: out_bf16[M,128] = bf16(A[M,K](lda) @ W + b) --------

__global__ __launch_bounds__(256) void gemm_mfma(
        const float* __restrict__ A, int lda, int K, int Kp,
        const unsigned short* __restrict__ Wt, const float* __restrict__ bias,
        unsigned short* __restrict__ out, int M) {
    __shared__ __align__(16) unsigned short As[64 * 200];

    int tid = threadIdx.x;
    int row0 = blockIdx.x * 64;

    {
        int r = tid >> 2;
        int q = tid & 3;
        int grow = row0 + r;
        int crow = grow < M ? grow : (M - 1);
        int kq = K >> 2;
        const float* ap = A + (size_t)crow * lda + q * kq;
        unsigned short* sp = As + r * Kp + q * kq;
        for (int k = 0; k < kq; k += 4) {
            float4 v = *(const float4*)(ap + k);
            sp[k + 0] = f2b(v.x); sp[k + 1] = f2b(v.y);
            sp[k + 2] = f2b(v.z); sp[k + 3] = f2b(v.w);
        }
    }
    __syncthreads();

    int wave = tid >> 6, lane = tid & 63;
    int m = lane & 15, quad = lane >> 4;

    f32x4 acc[8];
#pragma unroll
    for (int g = 0; g < 8; ++g) acc[g] = (f32x4){0.f, 0.f, 0.f, 0.f};

    int nsteps = K >> 5;
    for (int ks = 0; ks < nsteps; ++ks) {
        int k0 = ks * 32 + quad * 8;
        bf16x8 af = *(const bf16x8*)(As + (wave * 16 + m) * Kp + k0);
#pragma unroll
        for (int g = 0; g < 8; ++g) {
            bf16x8 bfr = *(const bf16x8*)(Wt + (size_t)(g * 16 + m) * K + k0);
            acc[g] = __builtin_amdgcn_mfma_f32_16x16x32_bf16(af, bfr, acc[g], 0, 0, 0);
        }
    }

#pragma unroll
    for (int g = 0; g < 8; ++g) {
        int col = g * 16 + m;
        float bv = bias[col];
#pragma unroll
        for (int r = 0; r < 4; ++r) {
            int grow = row0 + wave * 16 + quad * 4 + r;
            if (grow < M) out[(size_t)grow * 128 + col] = f2b(acc[g][r] + bv);
        }
    }
}

// ---------------- fused dual-view aggregation + combine + relu ----------------
// One wave per dst node; lane l handles features 2l, 2l+1 (uint = 2 bf16).

__global__ __launch_bounds__(256) void agg_kernel(
        const unsigned short* __restrict__ h1b, const unsigned short* __restrict__ h2b,
        const int* __restrict__ row_ptr, const unsigned short* __restrict__ esrc,
        const float* __restrict__ dhis, const float* __restrict__ D_inv,
        float* __restrict__ out_q, float* __restrict__ out_p, int n) {
    int wave = threadIdx.x >> 6, lane = threadIdx.x & 63;
    int d = blockIdx.x * 4 + wave;
    if (d >= n) return;

    const unsigned* r1 = (const unsigned*)h1b;   // [n][64]
    const unsigned* r2 = (const unsigned*)h2b;

    int e0 = row_ptr[d], e1 = row_ptr[d + 1];
    float a1x = 0.f, a1y = 0.f, g1x = 0.f, g1y = 0.f;
    float a2x = 0.f, a2y = 0.f, g2x = 0.f, g2y = 0.f;

    int e = e0;
    for (; e + 4 <= e1; e += 4) {
        int s0 = esrc[e], s1 = esrc[e + 1], s2 = esrc[e + 2], s3 = esrc[e + 3];
        float d0 = dhis[s0], d1 = dhis[s1], d2 = dhis[s2], d3 = dhis[s3];
        unsigned u10 = r1[(size_t)s0 * 64 + lane], u11 = r1[(size_t)s1 * 64 + lane];
        unsigned u12 = r1[(size_t)s2 * 64 + lane], u13 = r1[(size_t)s3 * 64 + lane];
        unsigned u20 = r2[(size_t)s0 * 64 + lane], u21 = r2[(size_t)s1 * 64 + lane];
        unsigned u22 = r2[(size_t)s2 * 64 + lane], u23 = r2[(size_t)s3 * 64 + lane];
        float v;
        v = blo(u10); a1x += v; g1x = fmaf(v, d0, g1x);
        v = bhi(u10); a1y += v; g1y = fmaf(v, d0, g1y);
        v = blo(u11); a1x += v; g1x = fmaf(v, d1, g1x);
        v = bhi(u11); a1y += v; g1y = fmaf(v, d1, g1y);
        v = blo(u12); a1x += v; g1x = fmaf(v, d2, g1x);
        v = bhi(u12); a1y += v; g1y = fmaf(v, d2, g1y);
        v = blo(u13); a1x += v; g1x = fmaf(v, d3, g1x);
        v = bhi(u13); a1y += v; g1y = fmaf(v, d3, g1y);
        v = blo(u20); a2x += v; g2x = fmaf(v, d0, g2x);
        v = bhi(u20); a2y += v; g2y = fmaf(v, d0, g2y);
        v = blo(u21); a2x += v; g2x = fmaf(v, d1, g2x);
        v = bhi(u21); a2y += v; g2y = fmaf(v, d1, g2y);
        v = blo(u22); a2x += v; g2x = fmaf(v, d2, g2x);
        v = bhi(u22); a2y += v; g2y = fmaf(v, d2, g2y);
        v = blo(u23); a2x += v; g2x = fmaf(v, d3, g2x);
        v = bhi(u23); a2y += v; g2y = fmaf(v, d3, g2y);
    }
    for (; e < e1; ++e) {
        int s = esrc[e];
        float ds = dhis[s];
        unsigned u1 = r1[(size_t)s * 64 + lane];
        unsigned u2 = r2[(size_t)s * 64 + lane];
        float v;
        v = blo(u1); a1x += v; g1x = fmaf(v, ds, g1x);
        v = bhi(u1); a1y += v; g1y = fmaf(v, ds, g1y);
        v = blo(u2); a2x += v; g2x = fmaf(v, ds, g2x);
        v = bhi(u2); a2y += v; g2y = fmaf(v, ds, g2y);
    }

    float dh = dhis[d];
    float di = D_inv[d];
    float dh2 = dh * dh;
    unsigned us1 = r1[(size_t)d * 64 + lane];
    unsigned us2 = r2[(size_t)d * 64 + lane];

    float o1x = fmaf(dh, g1x, fmaf(blo(us1), dh2, a2x * di));
    float o1y = fmaf(dh, g1y, fmaf(bhi(us1), dh2, a2y * di));
    float o2x = fmaf(dh, g2x, fmaf(blo(us2), dh2, a1x * di));
    float o2y = fmaf(dh, g2y, fmaf(bhi(us2), dh2, a1y * di));

    *(float2*)(out_q + (size_t)d * 384 + lane * 2) =
        make_float2(fmaxf(o1x, 0.f), fmaxf(o1y, 0.f));
    *(float2*)(out_p + (size_t)d * 384 + lane * 2) =
        make_float2(fmaxf(o2x, 0.f), fmaxf(o2y, 0.f));
}

// ---------------- launcher ----------------

extern "C" void kernel_launch(void* const* d_in, const int* in_sizes, int n_in,
                              void* d_out, int out_size, void* d_ws, size_t ws_size,
                              hipStream_t stream) {
    const float* x     = (const float*)d_in[0];
    const float* view2 = (const float*)d_in[1];
    const int*   eidx  = (const int*)d_in[2];
    const float* D_inv = (const float*)d_in[3];
    const float* W1 = (const float*)d_in[4];  const float* b1 = (const float*)d_in[5];
    const float* W2 = (const float*)d_in[6];  const float* b2 = (const float*)d_in[7];
    const float* W3 = (const float*)d_in[8];  const float* b3 = (const float*)d_in[9];
    const float* W4 = (const float*)d_in[10]; const float* b4 = (const float*)d_in[11];
    const float* W5 = (const float*)d_in[12]; const float* b5 = (const float*)d_in[13];
    const float* W6 = (const float*)d_in[14]; const float* b6 = (const float*)d_in[15];

    const int n = N_NODES;
    const int E = N_EDGES;
    const int nb = (n + 255) / 256;            // 196
    const int* src  = eidx;
    const int* dstv = eidx + E;

    char* ws = (char*)d_ws;
    size_t off = 0;
    auto alloc = [&](size_t bytes) -> void* {
        void* p = ws + off;
        off += (bytes + 255) & ~(size_t)255;
        return p;
    };
    int*   cnt     = (int*)alloc((size_t)n * 4);
    int*   row_ptr = (int*)alloc((size_t)(n + 1) * 4);
    float* dhis    = (float*)alloc((size_t)n * 4);
    int*   bsum    = (int*)alloc((size_t)nb * 4);
    int*   boff    = (int*)alloc((size_t)nb * 4);
    int*   bcnt    = (int*)alloc((size_t)NBUK * 4);
    unsigned* bbuf = (unsigned*)alloc((size_t)NBUK * BCAP * 4);
    unsigned short* esrc = (unsigned short*)alloc((size_t)E * 2);
    unsigned short* h1b = (unsigned short*)alloc((size_t)n * 128 * 2);
    unsigned short* h2b = (unsigned short*)alloc((size_t)n * 128 * 2);
    unsigned short* Wt1 = (unsigned short*)alloc((size_t)128 * 192 * 2);
    unsigned short* Wt4 = (unsigned short*)alloc((size_t)128 * 192 * 2);
    unsigned short* Wt2 = (unsigned short*)alloc((size_t)128 * 128 * 2);
    unsigned short* Wt3 = (unsigned short*)alloc((size_t)128 * 128 * 2);
    unsigned short* Wt5 = (unsigned short*)alloc((size_t)128 * 128 * 2);
    unsigned short* Wt6 = (unsigned short*)alloc((size_t)128 * 128 * 2);

    float* qb = (float*)d_out;
    float* pb = qb + (size_t)n * 384;

    // --- CSR build via bucket sort ---
    hipMemsetAsync(bcnt, 0, (size_t)NBUK * 4, stream);
    int eblocks = (E + 255) / 256;
    scatter_buckets<<<eblocks, 256, 0, stream>>>(src, dstv, E, bcnt, bbuf);
    bucket_count<<<NBUK, 256, 0, stream>>>(bcnt, bbuf, cnt, n);
    block_sums<<<nb, 256, 0, stream>>>(cnt, n, bsum, dhis);
    scan_bsums<<<1, 256, 0, stream>>>(bsum, nb, boff, row_ptr, n);
    block_scan<<<nb, 256, 0, stream>>>(cnt, n, boff, row_ptr);
    bucket_place<<<NBUK, 256, 0, stream>>>(bcnt, bbuf, row_ptr, esrc, n);

    // --- weight transposes (bf16), one launch ---
    {
        WP p0{W1, Wt1, 192}, p1{W4, Wt4, 192}, p2{W2, Wt2, 128};
        WP p3{W3, Wt3, 128}, p4{W5, Wt5, 128}, p5{W6, Wt6, 128};
        dim3 grid((128 * 192 + 255) / 256, 6);
        prep_all<<<grid, 256, 0, stream>>>(p0, p1, p2, p3, p4, p5);
    }

    int gblocks = (n + 63) / 64;
    int ablocks = (n + 3) / 4;

    // --- layer 1 ---
    gemm_mfma<<<gblocks, 256, 0, stream>>>(x,     D_IN, 192, 200, Wt1, b1, h1b, n);
    gemm_mfma<<<gblocks, 256, 0, stream>>>(view2, D_IN, 192, 200, Wt4, b4, h2b, n);
    agg_kernel<<<ablocks, 256, 0, stream>>>(h1b, h2b, row_ptr, esrc, dhis, D_inv, qb + 0, pb + 0, n);

    // --- layer 2 ---
    gemm_mfma<<<gblocks, 256, 0, stream>>>(qb, 384, 128, 136, Wt2, b2, h1b, n);
    gemm_mfma<<<gblocks, 256, 0, stream>>>(pb, 384, 128, 136, Wt5, b5, h2b, n);
    agg_kernel<<<ablocks, 256, 0, stream>>>(h1b, h2b, row_ptr, esrc, dhis, D_inv, qb + 128, pb + 128, n);

    // --- layer 3 ---
    gemm_mfma<<<gblocks, 256, 0, stream>>>(qb + 128, 384, 128, 136, Wt3, b3, h1b, n);
    gemm_mfma<<<gblocks, 256, 0, stream>>>(pb + 128, 384, 128, 136, Wt6, b6, h2b, n);
    agg_kernel<<<ablocks, 256, 0, stream>>>(h1b, h2b, row_ptr, esrc, dhis, D_inv, qb + 256, pb + 256, n);
}